// Round 5
// baseline (1298.931 us; speedup 1.0000x reference)
//
#include <hip/hip_runtime.h>
#include <hip/hip_bf16.h>
#include <math.h>

typedef __attribute__((ext_vector_type(8))) short bf16x8;
typedef __attribute__((ext_vector_type(4))) float f32x4;
typedef __attribute__((ext_vector_type(16))) float f32x16;
typedef __attribute__((ext_vector_type(4))) unsigned short ushort4v;

constexpr int Bsz = 16;

__device__ __forceinline__ float act_r(float v, int a) {
  if (a == 1) return v > 0.f ? v : 0.f;
  if (a == 2) return v >= 0.f ? v : 0.01f * v;
  return v;
}

__device__ __forceinline__ unsigned short f2bf(float x) {
  __hip_bfloat16 h = __float2bfloat16(x);   // RNE
  return __builtin_bit_cast(unsigned short, h);
}

// async global->LDS, 16B per lane; LDS dest must be wave-uniform base (+lane*16)
__device__ __forceinline__ void gll16(const unsigned short* g, unsigned short* l) {
  __builtin_amdgcn_global_load_lds(
      (const __attribute__((address_space(1))) unsigned int*)g,
      (__attribute__((address_space(3))) unsigned int*)l, 16, 0, 0);
}

// ---------------------------------------------------------------------------
// zprep: z1 f32 [16][192][16][16] -> bf16 [b][6][256 px][32 ic]
// ---------------------------------------------------------------------------
__global__ __launch_bounds__(256) void zprep_k(
    const float* __restrict__ z, unsigned short* __restrict__ zh)
{
  const int g = blockIdx.x * 256 + threadIdx.x;
  if (g >= 16 * 192 * 256) return;
  const int b  = g / 49152;
  const int rr = g - b * 49152;
  const int px = rr / 192;
  const int ic = rr - px * 192;
  const int o = ((b * 6 + (ic >> 5)) * 256 + px) * 32 + (ic & 31);
  zh[o] = f2bf(z[(b * 192 + ic) * 256 + px]);
}

// ---------------------------------------------------------------------------
// Weight preps (single bf16).  deconv src: [IC=192][OC][5][5];
// conv src: [OC][192][5][5].  dst: bf16 [j 25][icb 24][oc][8 ic]
// ---------------------------------------------------------------------------
__device__ __forceinline__ void dprep_one(
    const float* __restrict__ w, unsigned short* __restrict__ wh, int OC, int g)
{
  const int oc  = g % OC;
  const int rem = g / OC;
  const int icb = rem % 24;
  const int j   = rem / 24;
  bf16x8 hv;
  #pragma unroll
  for (int e = 0; e < 8; ++e)
    hv[e] = (short)f2bf(w[((icb * 8 + e) * OC + oc) * 25 + j]);
  *(bf16x8*)&wh[((j * 24 + icb) * OC + oc) * 8] = hv;
}

__global__ __launch_bounds__(256) void wprep1_k(
    const float* __restrict__ s0, const float* __restrict__ s1,
    const float* __restrict__ s2, unsigned short* __restrict__ wh)
{
  const int bid = blockIdx.x;
  const int seg = bid / 450;
  const int g   = (bid - seg * 450) * 256 + threadIdx.x;
  if (g >= 192 * 24 * 25) return;
  const float* src = seg == 0 ? s0 : (seg == 1 ? s1 : s2);
  dprep_one(src, wh + (size_t)seg * 921600, 192, g);
}

__global__ __launch_bounds__(256) void wprep_d_k(
    const float* __restrict__ w, unsigned short* __restrict__ wh, int OC)
{
  const int g = blockIdx.x * 256 + threadIdx.x;
  if (g >= OC * 24 * 25) return;
  dprep_one(w, wh, OC, g);
}

__global__ __launch_bounds__(256) void wprep_t_k(
    const float* __restrict__ w, unsigned short* __restrict__ wh)
{
  const int g = blockIdx.x * 256 + threadIdx.x;
  if (g >= 576 * 24 * 25) return;
  const int oc  = g % 576;
  const int rem = g / 576;
  const int icb = rem % 24;
  const int j   = rem / 24;
  bf16x8 hv;
  #pragma unroll
  for (int e = 0; e < 8; ++e)
    hv[e] = (short)f2bf(w[oc * 4800 + (icb * 8 + e) * 25 + j]);
  *(bf16x8*)&wh[((j * 24 + icb) * 576 + oc) * 8] = hv;
}

// ---------------------------------------------------------------------------
// MFMA transposed conv k5 s2 p2 op1 (H x H -> 2H x 2H), single bf16, f32 acc.
// 2 input rows per wave (8 per block), 32 oc per block.
// X: [b][6][H][H][32] bf16.  W: [j][24][OC][8] bf16.
// OL=0: output [b][cg32][py][px][32ic]; OL=1: output [b][qg8][py][px][8ic]
// (quarter-major, so conv3's global_load_lds prefetch is lane-contiguous).
// ---------------------------------------------------------------------------
template<int H, int OMODE, int OL>
__global__ __launch_bounds__(256, 2) void deconv2_k(
    const unsigned short* __restrict__ xh, long x_brs,
    const unsigned short* __restrict__ wh, long w_brs,
    const float* __restrict__ b0, const float* __restrict__ b1,
    const float* __restrict__ b2,
    unsigned short* __restrict__ yh, long y_brs,
    float* __restrict__ mvp, int OC, int a0, int a1, int a2)
{
  constexpr int NF = H / 16;
  __shared__ __align__(16) unsigned short xs[10][H + 2][32];
  __shared__ float red[4][32];

  const int zz = blockIdx.z;
  const int br = zz >> 4;
  const int b  = zz & 15;
  const int by = blockIdx.y;
  const int r0 = by * 8;
  const int oc0 = blockIdx.x * 32;
  const int t  = threadIdx.x;
  const int wv = t >> 6;
  const int l  = t & 63;
  const int lg = l >> 4;
  const int ln = l & 15;

  const unsigned short* xhp = xh + (long)br * x_brs;
  const unsigned short* whp = wh + (long)br * w_brs;
  const float* bias = br == 0 ? b0 : (br == 1 ? b1 : b2);
  const int act = br == 0 ? a0 : (br == 1 ? a1 : a2);

  f32x4 acc[2][4][2][NF];
  #pragma unroll
  for (int rr = 0; rr < 2; ++rr)
    #pragma unroll
    for (int p = 0; p < 4; ++p)
      #pragma unroll
      for (int of = 0; of < 2; ++of)
        #pragma unroll
        for (int nf = 0; nf < NF; ++nf)
          acc[rr][p][of][nf] = (f32x4){0.f, 0.f, 0.f, 0.f};

  const bf16x8 zero8 = {0,0,0,0,0,0,0,0};

  for (int c = 0; c < 6; ++c) {
    __syncthreads();
    constexpr int DC = 10 * H * 4;
    #pragma unroll
    for (int k = 0; k < (DC + 255) / 256; ++k) {
      const int li = t + k * 256;
      if (li < DC) {
        const int part = li & 3;
        const int col  = (li >> 2) & (H - 1);
        const int row  = li / (4 * H);
        const int y    = r0 - 1 + row;
        bf16x8 v = zero8;
        if ((unsigned)y < (unsigned)H)
          v = *(const bf16x8*)&xhp[(((size_t)(b * 6 + c) * H + y) * H + col) * 32 + part * 8];
        *(bf16x8*)&xs[row][col + 1][part * 8] = v;
      }
    }
    if (t < 80) {   // halo cols 0 and H+1
      const int row = t >> 3;
      const int cc  = t & 7;
      const int col = (cc >> 2) ? (H + 1) : 0;
      *(bf16x8*)&xs[row][col][(cc & 3) * 8] = zero8;
    }
    __syncthreads();

    #pragma unroll
    for (int j = 0; j < 25; ++j) {
      const int ky = j / 5, kx = j % 5;
      const int sy = ky & 1, sx = kx & 1;
      const int dy = (2 + sy - ky) / 2;
      const int dx = (2 + sx - kx) / 2;
      const int p  = sy * 2 + sx;

      bf16x8 ah[2];
      const int wbase = ((j * 24 + c * 4 + lg) * OC + oc0 + ln) * 8;
      #pragma unroll
      for (int of = 0; of < 2; ++of)
        ah[of] = *(const bf16x8*)&whp[wbase + of * 128];
      #pragma unroll
      for (int rr = 0; rr < 2; ++rr) {
        const int rl = 2 * wv + rr + 1 + dy;
        bf16x8 bh[NF];
        #pragma unroll
        for (int nf = 0; nf < NF; ++nf) {
          const int cl = 1 + nf * 16 + ln + dx;
          bh[nf] = *(const bf16x8*)&xs[rl][cl][lg * 8];
        }
        #pragma unroll
        for (int of = 0; of < 2; ++of)
          #pragma unroll
          for (int nf = 0; nf < NF; ++nf)
            acc[rr][p][of][nf] = __builtin_amdgcn_mfma_f32_16x16x32_bf16(
                ah[of], bh[nf], acc[rr][p][of][nf], 0, 0, 0);
      }
    }
  }

  if (OMODE == 1) {
    const int OCG = OC >> 5;
    float bv[2][4];
    #pragma unroll
    for (int of = 0; of < 2; ++of)
      #pragma unroll
      for (int r = 0; r < 4; ++r)
        bv[of][r] = bias[oc0 + of * 16 + lg * 4 + r];
    unsigned short* yhp = yh + (long)br * y_brs;
    #pragma unroll
    for (int rr = 0; rr < 2; ++rr) {
      const int iy = r0 + 2 * wv + rr;
      #pragma unroll
      for (int sy = 0; sy < 2; ++sy)
        #pragma unroll
        for (int sx = 0; sx < 2; ++sx) {
          const int p  = sy * 2 + sx;
          const int oy = 2 * iy + sy;
          #pragma unroll
          for (int of = 0; of < 2; ++of) {
            const int ocb = oc0 + of * 16 + lg * 4;
            const int cg  = ocb >> 5;
            const int co  = ocb & 31;
            #pragma unroll
            for (int nf = 0; nf < NF; ++nf) {
              const int ox = 2 * (nf * 16 + ln) + sx;
              ushort4v hv;
              #pragma unroll
              for (int r = 0; r < 4; ++r)
                hv[r] = f2bf(act_r(acc[rr][p][of][nf][r] + bv[of][r], act));
              size_t idx;
              if (OL) {
                const int qg = cg * 4 + (co >> 3);
                idx = (((size_t)(b * (OC >> 3) + qg) * (4 * H * H)) +
                       (size_t)oy * (2 * H) + ox) * 8 + (co & 7);
              } else {
                idx = (((size_t)(b * OCG + cg) * (4 * H * H)) +
                       (size_t)oy * (2 * H) + ox) * 32 + co;
              }
              *(ushort4v*)&yhp[idx] = hv;
            }
          }
        }
    }
  } else {
    #pragma unroll
    for (int of = 0; of < 2; ++of)
      #pragma unroll
      for (int r = 0; r < 4; ++r) {
        float m = -3.402823466e38f;
        #pragma unroll
        for (int rr = 0; rr < 2; ++rr)
          #pragma unroll
          for (int p = 0; p < 4; ++p)
            #pragma unroll
            for (int nf = 0; nf < NF; ++nf)
              m = fmaxf(m, acc[rr][p][of][nf][r]);
        #pragma unroll
        for (int off = 1; off < 16; off <<= 1)
          m = fmaxf(m, __shfl_xor(m, off));
        if (ln == 0)
          red[wv][of * 16 + lg * 4 + r] = m + bias[oc0 + of * 16 + lg * 4 + r];
      }
    __syncthreads();
    if (t < 32) {
      const float v = fmaxf(fmaxf(red[0][t], red[1][t]), fmaxf(red[2][t], red[3][t]));
      mvp[((b * 4) + by) * OC + oc0 + t] = v;
    }
  }
}

// ---------------------------------------------------------------------------
// Conv k5 s1 p2, 192 -> 576, 64x64.  mfma_f32_16x16x32, acc[4][4].
// This round: (a) col pad 68->80 so the ic-quarter stride is 1280 B == 0
// mod 128 -> every 16-lane group tiles all 32 banks from bank 0 (kills the
// 2.2e7 conflicts); LDS 40.96 KB also pins exactly 3 blocks/CU.
// (b) per-wave (ky,kx) rotation (bijective) so the 4 waves issue their
// ds_read bursts and MFMA clusters out of phase -> LDS pipe and MFMA pipe
// overlap across waves instead of convoying (measured: phase time ~= sum of
// pipes, not max).  (c) T5 setprio around the MFMA cluster now that waves
// have role diversity.
// X: [b][24 qg][64][64][8].  W: [j][24][576][8].
// ---------------------------------------------------------------------------
__global__ __launch_bounds__(256, 3) void conv3_k(
    const unsigned short* __restrict__ gxh,
    const unsigned short* __restrict__ gwh,
    const float* __restrict__ bias, float* __restrict__ out, int act)
{
  __shared__ __align__(16) unsigned short xs[8][4][80][8];

  const int bid  = blockIdx.x;
  const int orig = (bid & 7) * 288 + (bid >> 3);   // ocg-major chunks per XCD
  const int ocg  = orig >> 8;
  const int rem  = orig & 255;
  const int b    = rem >> 4;
  const int band = rem & 15;
  const int y0   = band * 4;
  const int oc0  = ocg * 64;
  const int t    = threadIdx.x;
  const int wv   = t >> 6;
  const int l    = t & 63;
  const int lg   = l >> 4;      // ic 8-group (quarter) within the 32-ic phase
  const int ln   = l & 15;

  f32x4 acc[4][4];
  #pragma unroll
  for (int of = 0; of < 4; ++of)
    #pragma unroll
    for (int pf = 0; pf < 4; ++pf)
      acc[of][pf] = (f32x4){0.f, 0.f, 0.f, 0.f};

  // one-time zero of the tile (covers halo cols + OOB rows; those cells are
  // never rewritten by the gll staging in any phase)
  {
    unsigned short* fx = (unsigned short*)xs;
    const bf16x8 z8 = {0,0,0,0,0,0,0,0};
    #pragma unroll
    for (int k = 0; k < 10; ++k) {
      const int li = t + k * 256;
      if (li < 2560) *(bf16x8*)&fx[li * 8] = z8;
    }
  }

  for (int c = 0; c < 6; ++c) {
    __syncthreads();   // prev compute done (and init-zero visible, c==0)
    // stage 8 rows x 4 quarters: 32 gll, 8 per wave; lane = column
    #pragma unroll
    for (int k = 0; k < 8; ++k) {
      const int idx = k * 4 + wv;
      const int row = idx >> 2, q = idx & 3;
      const int y = y0 - 2 + row;
      if ((unsigned)y < 64u) {
        const unsigned short* g = &gxh[
            ((((size_t)b * 24 + c * 4 + q) << 12) + ((size_t)y << 6) + l) * 8];
        gll16(g, &xs[row][q][2][0]);
      }
    }
    __syncthreads();   // implicit vmcnt(0): staging visible

    #pragma unroll
    for (int ky = 0; ky < 5; ++ky) {
      int ky2 = ky + wv; if (ky2 >= 5) ky2 -= 5;   // per-wave rotation
      const int rl = wv + ky2;
      #pragma unroll
      for (int kx = 0; kx < 5; ++kx) {
        int kx2 = kx + wv; if (kx2 >= 5) kx2 -= 5;
        const int jj = ky2 * 5 + kx2;
        bf16x8 ah[4], bx[4];
        const int wbase = ((jj * 24 + c * 4 + lg) * 576 + oc0 + ln) * 8;
        #pragma unroll
        for (int of = 0; of < 4; ++of)
          ah[of] = *(const bf16x8*)&gwh[wbase + of * 128];
        #pragma unroll
        for (int pf = 0; pf < 4; ++pf)
          bx[pf] = *(const bf16x8*)&xs[rl][lg][pf * 16 + ln + kx2][0];
        __builtin_amdgcn_s_setprio(1);
        #pragma unroll
        for (int of = 0; of < 4; ++of)
          #pragma unroll
          for (int pf = 0; pf < 4; ++pf)
            acc[of][pf] = __builtin_amdgcn_mfma_f32_16x16x32_bf16(
                ah[of], bx[pf], acc[of][pf], 0, 0, 0);
        __builtin_amdgcn_s_setprio(0);
      }
    }
  }

  // epilogue: D mapping (16x16): col = l&15 (px), row = (l>>4)*4 + r (oc)
  const int y = y0 + wv;
  #pragma unroll
  for (int of = 0; of < 4; ++of)
    #pragma unroll
    for (int r = 0; r < 4; ++r) {
      const int oc = oc0 + of * 16 + lg * 4 + r;
      const float bv = bias[oc];
      float* po = &out[(((size_t)(b * 576 + oc) * 64) + y) * 64 + ln];
      #pragma unroll
      for (int pf = 0; pf < 4; ++pf)
        po[16 * pf] = act_r(acc[of][pf][r] + bv, act);
    }
}

// ---------------------------------------------------------------------------
// Ablation probes (diagnostic, outputs to dead workspace; 768-block grid =
// one full residency round at 3 blocks/CU, same LDS footprint as conv3_k).
// MODE 1: pure MFMA chain.  MODE 0: + per-j global A loads.
// MODE 2: + gll staging + per-j ds_reads (A preloaded once).
// ---------------------------------------------------------------------------
template<int MODE>
__global__ __launch_bounds__(256, 3) void probe_k(
    const unsigned short* __restrict__ gxh,
    const unsigned short* __restrict__ gwh,
    float* __restrict__ scratch)
{
  __shared__ __align__(16) unsigned short xs[8][4][80][8];
  const int bid  = blockIdx.x;
  const int ocg  = bid >> 8;
  const int rem  = bid & 255;
  const int b    = rem >> 4;
  const int band = rem & 15;
  const int y0   = band * 4;
  const int oc0  = ocg * 64;
  const int t    = threadIdx.x;
  const int wv   = t >> 6;
  const int l    = t & 63;
  const int lg   = l >> 4;
  const int ln   = l & 15;

  ((volatile unsigned short*)xs)[t] = 0;   // keep LDS allocated in all modes

  f32x4 acc[4][4];
  #pragma unroll
  for (int of = 0; of < 4; ++of)
    #pragma unroll
    for (int pf = 0; pf < 4; ++pf)
      acc[of][pf] = (f32x4){0.f, 0.f, 0.f, 0.f};

  bf16x8 ah0[4];
  {
    const int wb0 = ((lg)*576 + oc0 + ln) * 8;
    #pragma unroll
    for (int of = 0; of < 4; ++of)
      ah0[of] = *(const bf16x8*)&gwh[wb0 + of * 128];
  }

  for (int c = 0; c < 6; ++c) {
    if (MODE == 2) {
      __syncthreads();
      #pragma unroll
      for (int k = 0; k < 8; ++k) {
        const int idx = k * 4 + wv;
        const int row = idx >> 2, q = idx & 3;
        const int y = y0 - 2 + row;
        if ((unsigned)y < 64u) {
          const unsigned short* g = &gxh[
              ((((size_t)b * 24 + c * 4 + q) << 12) + ((size_t)y << 6) + l) * 8];
          gll16(g, &xs[row][q][2][0]);
        }
      }
      __syncthreads();
    }
    #pragma unroll
    for (int j = 0; j < 25; ++j) {
      bf16x8 ah[4], bx[4];
      if (MODE == 0) {
        const int wbase = ((j * 24 + c * 4 + lg) * 576 + oc0 + ln) * 8;
        #pragma unroll
        for (int of = 0; of < 4; ++of) ah[of] = *(const bf16x8*)&gwh[wbase + of * 128];
        #pragma unroll
        for (int pf = 0; pf < 4; ++pf) bx[pf] = ah0[pf];
      } else if (MODE == 1) {
        #pragma unroll
        for (int of = 0; of < 4; ++of) ah[of] = ah0[of];
        #pragma unroll
        for (int pf = 0; pf < 4; ++pf) bx[pf] = ah0[pf];
      } else {
        const int ky = j / 5, kx = j % 5;
        const int rl = wv + ky;
        #pragma unroll
        for (int of = 0; of < 4; ++of) ah[of] = ah0[of];
        #pragma unroll
        for (int pf = 0; pf < 4; ++pf)
          bx[pf] = *(const bf16x8*)&xs[rl][lg][pf * 16 + ln + kx][0];
      }
      #pragma unroll
      for (int of = 0; of < 4; ++of)
        #pragma unroll
        for (int pf = 0; pf < 4; ++pf)
          acc[of][pf] = __builtin_amdgcn_mfma_f32_16x16x32_bf16(
              ah[of], bx[pf], acc[of][pf], 0, 0, 0);
    }
  }

  f32x4 s = (f32x4){0.f, 0.f, 0.f, 0.f};
  #pragma unroll
  for (int of = 0; of < 4; ++of)
    #pragma unroll
    for (int pf = 0; pf < 4; ++pf)
      s += acc[of][pf];
  *(f32x4*)&scratch[((size_t)bid * 256 + t) * 4] = s;
}

// ---------------------------------------------------------------------------
// Weights head: reduce 4 tile-maxes, leaky, 1x1 conv (576x576), softmax K=3
// ---------------------------------------------------------------------------
__global__ __launch_bounds__(256) void head_k(
    const float* __restrict__ mvp, const float* __restrict__ w3,
    const float* __restrict__ b3, float* __restrict__ outw)
{
  __shared__ float lv[576];
  __shared__ float yv[576];
  const int b = blockIdx.x;
  const int t = threadIdx.x;
  for (int i = t; i < 576; i += 256) {
    float m = mvp[(b * 4 + 0) * 576 + i];
    #pragma unroll
    for (int ti = 1; ti < 4; ++ti)
      m = fmaxf(m, mvp[(b * 4 + ti) * 576 + i]);
    lv[i] = m >= 0.f ? m : 0.01f * m;
  }
  __syncthreads();
  for (int oc = t; oc < 576; oc += 256) {
    float s = b3[oc];
    for (int c = 0; c < 576; ++c) s += w3[oc * 576 + c] * lv[c];
    yv[oc] = s;
  }
  __syncthreads();
  if (t < 192) {
    const float v0 = yv[t], v1 = yv[192 + t], v2 = yv[384 + t];
    const float mx = fmaxf(v0, fmaxf(v1, v2));
    const float e0 = expf(v0 - mx), e1 = expf(v1 - mx), e2 = expf(v2 - mx);
    const float inv = 1.f / (e0 + e1 + e2);
    outw[b * 576 + t]       = e0 * inv;
    outw[b * 576 + 192 + t] = e1 * inv;
    outw[b * 576 + 384 + t] = e2 * inv;
  }
}

extern "C" void kernel_launch(void* const* d_in, const int* in_sizes, int n_in,
                              void* d_out, int out_size, void* d_ws, size_t ws_size,
                              hipStream_t stream)
{
  (void)in_sizes; (void)n_in; (void)out_size; (void)ws_size;

  const float* z1    = (const float*)d_in[0];
  const float* gs_w1 = (const float*)d_in[1];
  const float* gs_b1 = (const float*)d_in[2];
  const float* gs_w2 = (const float*)d_in[3];
  const float* gs_b2 = (const float*)d_in[4];
  const float* gs_w3 = (const float*)d_in[5];
  const float* gs_b3 = (const float*)d_in[6];
  const float* gm_w1 = (const float*)d_in[7];
  const float* gm_b1 = (const float*)d_in[8];
  const float* gm_w2 = (const float*)d_in[9];
  const float* gm_b2 = (const float*)d_in[10];
  const float* gm_w3 = (const float*)d_in[11];
  const float* gm_b3 = (const float*)d_in[12];
  const float* gw_w1 = (const float*)d_in[13];
  const float* gw_b1 = (const float*)d_in[14];
  const float* gw_w2 = (const float*)d_in[15];
  const float* gw_b2 = (const float*)d_in[16];
  const float* gw_w3 = (const float*)d_in[17];
  const float* gw_b3 = (const float*)d_in[18];

  // workspace layout (ushort units), total ~38 MB
  unsigned short* p = (unsigned short*)d_ws;
  unsigned short* Z   = p; p += 786432;
  unsigned short* A1  = p; p += (size_t)3 * 3145728;   // 3 branches
  unsigned short* A2  = p; p += 12582912;
  unsigned short* W1  = p; p += (size_t)3 * 921600;    // 3 branch w1; dead
                                                       // after deconv1 ->
                                                       // probe scratch
  unsigned short* Wb  = p; p += 2764800;               // reusable big slot
  float* MVp = (float*)p;                              // [16][4][576]

  float* o_sigma = (float*)d_out;
  float* o_means = o_sigma + (size_t)Bsz * 576 * 64 * 64;
  float* o_w     = o_means + (size_t)Bsz * 576 * 64 * 64;

  dim3 blk(256);

  zprep_k<<<dim3(3072), blk, 0, stream>>>(z1, Z);
  wprep1_k<<<dim3(1350), blk, 0, stream>>>(gs_w1, gm_w1, gw_w1, W1);

  // deconv1, all 3 branches in one launch (acts: relu, leaky, leaky)
  deconv2_k<16,1,0><<<dim3(6,2,48), blk, 0, stream>>>(
      Z, 0, W1, 921600, gs_b1, gm_b1, gw_b1,
      A1, 3145728, nullptr, 192, 1, 2, 2);

  // sigma branch
  wprep_d_k<<<dim3(450), blk, 0, stream>>>(gs_w2, Wb, 192);
  deconv2_k<32,1,1><<<dim3(6,4,16), blk, 0, stream>>>(
      A1, 0, Wb, 0, gs_b2, gs_b2, gs_b2,
      A2, 0, nullptr, 192, 1, 1, 1);
  wprep_t_k<<<dim3(1350), blk, 0, stream>>>(gs_w3, Wb);
  conv3_k<<<dim3(2304), blk, 0, stream>>>(A2, Wb, gs_b3, o_sigma, 1);

  // means branch
  wprep_d_k<<<dim3(450), blk, 0, stream>>>(gm_w2, Wb, 192);
  deconv2_k<32,1,1><<<dim3(6,4,16), blk, 0, stream>>>(
      A1 + (size_t)3145728, 0, Wb, 0, gm_b2, gm_b2, gm_b2,
      A2, 0, nullptr, 192, 2, 2, 2);
  wprep_t_k<<<dim3(1350), blk, 0, stream>>>(gm_w3, Wb);
  conv3_k<<<dim3(2304), blk, 0, stream>>>(A2, Wb, gm_b3, o_means, 0);

  // weights branch
  wprep_d_k<<<dim3(1350), blk, 0, stream>>>(gw_w2, Wb, 576);
  deconv2_k<32,2,0><<<dim3(18,4,16), blk, 0, stream>>>(
      A1 + (size_t)2 * 3145728, 0, Wb, 0,
      gw_b2, gw_b2, gw_b2, nullptr, 0, MVp, 576, 0, 0, 0);
  head_k<<<dim3(16), blk, 0, stream>>>(MVp, gw_w3, gw_b3, o_w);

  // diagnostic probes (timing rows only; outputs go to dead W1 region)
  float* scr = (float*)W1;
  probe_k<1><<<dim3(768), blk, 0, stream>>>(A2, Wb, scr);
  probe_k<0><<<dim3(768), blk, 0, stream>>>(A2, Wb, scr);
  probe_k<2><<<dim3(768), blk, 0, stream>>>(A2, Wb, scr);
}

// Round 6
// 1044.453 us; speedup vs baseline: 1.2436x; 1.2436x over previous
//
#include <hip/hip_runtime.h>
#include <hip/hip_bf16.h>
#include <math.h>

typedef __attribute__((ext_vector_type(8))) short bf16x8;
typedef __attribute__((ext_vector_type(4))) float f32x4;
typedef __attribute__((ext_vector_type(16))) float f32x16;
typedef __attribute__((ext_vector_type(4))) unsigned short ushort4v;

constexpr int Bsz = 16;

__device__ __forceinline__ float act_r(float v, int a) {
  if (a == 1) return v > 0.f ? v : 0.f;
  if (a == 2) return v >= 0.f ? v : 0.01f * v;
  return v;
}

__device__ __forceinline__ unsigned short f2bf(float x) {
  __hip_bfloat16 h = __float2bfloat16(x);   // RNE
  return __builtin_bit_cast(unsigned short, h);
}

// async global->LDS, 16B per lane; LDS dest must be wave-uniform base (+lane*16)
__device__ __forceinline__ void gll16(const unsigned short* g, unsigned short* l) {
  __builtin_amdgcn_global_load_lds(
      (const __attribute__((address_space(1))) unsigned int*)g,
      (__attribute__((address_space(3))) unsigned int*)l, 16, 0, 0);
}

// ---------------------------------------------------------------------------
// zprep: z1 f32 [16][192][16][16] -> bf16 [b][6][256 px][32 ic]
// ---------------------------------------------------------------------------
__global__ __launch_bounds__(256) void zprep_k(
    const float* __restrict__ z, unsigned short* __restrict__ zh)
{
  const int g = blockIdx.x * 256 + threadIdx.x;
  if (g >= 16 * 192 * 256) return;
  const int b  = g / 49152;
  const int rr = g - b * 49152;
  const int px = rr / 192;
  const int ic = rr - px * 192;
  const int o = ((b * 6 + (ic >> 5)) * 256 + px) * 32 + (ic & 31);
  zh[o] = f2bf(z[(b * 192 + ic) * 256 + px]);
}

// ---------------------------------------------------------------------------
// Weight preps (single bf16).  deconv src: [IC=192][OC][5][5];
// conv src: [OC][192][5][5].  dst: bf16 [j 25][icb 24][oc][8 ic]
// ---------------------------------------------------------------------------
__device__ __forceinline__ void dprep_one(
    const float* __restrict__ w, unsigned short* __restrict__ wh, int OC, int g)
{
  const int oc  = g % OC;
  const int rem = g / OC;
  const int icb = rem % 24;
  const int j   = rem / 24;
  bf16x8 hv;
  #pragma unroll
  for (int e = 0; e < 8; ++e)
    hv[e] = (short)f2bf(w[((icb * 8 + e) * OC + oc) * 25 + j]);
  *(bf16x8*)&wh[((j * 24 + icb) * OC + oc) * 8] = hv;
}

__global__ __launch_bounds__(256) void wprep1_k(
    const float* __restrict__ s0, const float* __restrict__ s1,
    const float* __restrict__ s2, unsigned short* __restrict__ wh)
{
  const int bid = blockIdx.x;
  const int seg = bid / 450;
  const int g   = (bid - seg * 450) * 256 + threadIdx.x;
  if (g >= 192 * 24 * 25) return;
  const float* src = seg == 0 ? s0 : (seg == 1 ? s1 : s2);
  dprep_one(src, wh + (size_t)seg * 921600, 192, g);
}

__global__ __launch_bounds__(256) void wprep_d_k(
    const float* __restrict__ w, unsigned short* __restrict__ wh, int OC)
{
  const int g = blockIdx.x * 256 + threadIdx.x;
  if (g >= OC * 24 * 25) return;
  dprep_one(w, wh, OC, g);
}

__global__ __launch_bounds__(256) void wprep_t_k(
    const float* __restrict__ w, unsigned short* __restrict__ wh)
{
  const int g = blockIdx.x * 256 + threadIdx.x;
  if (g >= 576 * 24 * 25) return;
  const int oc  = g % 576;
  const int rem = g / 576;
  const int icb = rem % 24;
  const int j   = rem / 24;
  bf16x8 hv;
  #pragma unroll
  for (int e = 0; e < 8; ++e)
    hv[e] = (short)f2bf(w[oc * 4800 + (icb * 8 + e) * 25 + j]);
  *(bf16x8*)&wh[((j * 24 + icb) * 576 + oc) * 8] = hv;
}

// ---------------------------------------------------------------------------
// MFMA transposed conv k5 s2 p2 op1 (H x H -> 2H x 2H), single bf16, f32 acc.
// RPW input rows per wave (4*RPW per block), 32 oc per block.
// X: [b][6][H][H][32] bf16.  W: [j][24][OC][8] bf16.
// OL=0: output [b][cg32][py][px][32ic]; OL=1: output [b][qg8][py][px][8ic]
// (quarter-major, so conv3's global_load_lds prefetch is lane-contiguous).
// RPW=1 halves the band -> 2x grid for the small sigma/means launches
// (384 blocks = 1.5/CU grid-starved -> 768 = clean 3/CU).
// ---------------------------------------------------------------------------
template<int H, int OMODE, int OL, int RPW>
__global__ __launch_bounds__(256, 2) void deconv2_k(
    const unsigned short* __restrict__ xh, long x_brs,
    const unsigned short* __restrict__ wh, long w_brs,
    const float* __restrict__ b0, const float* __restrict__ b1,
    const float* __restrict__ b2,
    unsigned short* __restrict__ yh, long y_brs,
    float* __restrict__ mvp, int OC, int a0, int a1, int a2)
{
  constexpr int NF = H / 16;
  constexpr int R  = 4 * RPW;          // input rows per block
  __shared__ __align__(16) unsigned short xs[R + 2][H + 2][32];
  __shared__ float red[4][32];

  const int zz = blockIdx.z;
  const int br = zz >> 4;
  const int b  = zz & 15;
  const int by = blockIdx.y;
  const int r0 = by * R;
  const int oc0 = blockIdx.x * 32;
  const int t  = threadIdx.x;
  const int wv = t >> 6;
  const int l  = t & 63;
  const int lg = l >> 4;
  const int ln = l & 15;

  const unsigned short* xhp = xh + (long)br * x_brs;
  const unsigned short* whp = wh + (long)br * w_brs;
  const float* bias = br == 0 ? b0 : (br == 1 ? b1 : b2);
  const int act = br == 0 ? a0 : (br == 1 ? a1 : a2);

  f32x4 acc[RPW][4][2][NF];
  #pragma unroll
  for (int rr = 0; rr < RPW; ++rr)
    #pragma unroll
    for (int p = 0; p < 4; ++p)
      #pragma unroll
      for (int of = 0; of < 2; ++of)
        #pragma unroll
        for (int nf = 0; nf < NF; ++nf)
          acc[rr][p][of][nf] = (f32x4){0.f, 0.f, 0.f, 0.f};

  const bf16x8 zero8 = {0,0,0,0,0,0,0,0};

  for (int c = 0; c < 6; ++c) {
    __syncthreads();
    constexpr int DC = (R + 2) * H * 4;
    #pragma unroll
    for (int k = 0; k < (DC + 255) / 256; ++k) {
      const int li = t + k * 256;
      if (li < DC) {
        const int part = li & 3;
        const int col  = (li >> 2) & (H - 1);
        const int row  = li / (4 * H);
        const int y    = r0 - 1 + row;
        bf16x8 v = zero8;
        if ((unsigned)y < (unsigned)H)
          v = *(const bf16x8*)&xhp[(((size_t)(b * 6 + c) * H + y) * H + col) * 32 + part * 8];
        *(bf16x8*)&xs[row][col + 1][part * 8] = v;
      }
    }
    if (t < 8 * (R + 2)) {   // halo cols 0 and H+1
      const int row = t >> 3;
      const int cc  = t & 7;
      const int col = (cc >> 2) ? (H + 1) : 0;
      *(bf16x8*)&xs[row][col][(cc & 3) * 8] = zero8;
    }
    __syncthreads();

    #pragma unroll
    for (int j = 0; j < 25; ++j) {
      const int ky = j / 5, kx = j % 5;
      const int sy = ky & 1, sx = kx & 1;
      const int dy = (2 + sy - ky) / 2;
      const int dx = (2 + sx - kx) / 2;
      const int p  = sy * 2 + sx;

      bf16x8 ah[2];
      const int wbase = ((j * 24 + c * 4 + lg) * OC + oc0 + ln) * 8;
      #pragma unroll
      for (int of = 0; of < 2; ++of)
        ah[of] = *(const bf16x8*)&whp[wbase + of * 128];
      #pragma unroll
      for (int rr = 0; rr < RPW; ++rr) {
        const int rl = RPW * wv + rr + 1 + dy;
        bf16x8 bh[NF];
        #pragma unroll
        for (int nf = 0; nf < NF; ++nf) {
          const int cl = 1 + nf * 16 + ln + dx;
          bh[nf] = *(const bf16x8*)&xs[rl][cl][lg * 8];
        }
        #pragma unroll
        for (int of = 0; of < 2; ++of)
          #pragma unroll
          for (int nf = 0; nf < NF; ++nf)
            acc[rr][p][of][nf] = __builtin_amdgcn_mfma_f32_16x16x32_bf16(
                ah[of], bh[nf], acc[rr][p][of][nf], 0, 0, 0);
      }
    }
  }

  if (OMODE == 1) {
    const int OCG = OC >> 5;
    float bv[2][4];
    #pragma unroll
    for (int of = 0; of < 2; ++of)
      #pragma unroll
      for (int r = 0; r < 4; ++r)
        bv[of][r] = bias[oc0 + of * 16 + lg * 4 + r];
    unsigned short* yhp = yh + (long)br * y_brs;
    #pragma unroll
    for (int rr = 0; rr < RPW; ++rr) {
      const int iy = r0 + RPW * wv + rr;
      #pragma unroll
      for (int sy = 0; sy < 2; ++sy)
        #pragma unroll
        for (int sx = 0; sx < 2; ++sx) {
          const int p  = sy * 2 + sx;
          const int oy = 2 * iy + sy;
          #pragma unroll
          for (int of = 0; of < 2; ++of) {
            const int ocb = oc0 + of * 16 + lg * 4;
            const int cg  = ocb >> 5;
            const int co  = ocb & 31;
            #pragma unroll
            for (int nf = 0; nf < NF; ++nf) {
              const int ox = 2 * (nf * 16 + ln) + sx;
              ushort4v hv;
              #pragma unroll
              for (int r = 0; r < 4; ++r)
                hv[r] = f2bf(act_r(acc[rr][p][of][nf][r] + bv[of][r], act));
              size_t idx;
              if (OL) {
                const int qg = cg * 4 + (co >> 3);
                idx = (((size_t)(b * (OC >> 3) + qg) * (4 * H * H)) +
                       (size_t)oy * (2 * H) + ox) * 8 + (co & 7);
              } else {
                idx = (((size_t)(b * OCG + cg) * (4 * H * H)) +
                       (size_t)oy * (2 * H) + ox) * 32 + co;
              }
              *(ushort4v*)&yhp[idx] = hv;
            }
          }
        }
    }
  } else {
    #pragma unroll
    for (int of = 0; of < 2; ++of)
      #pragma unroll
      for (int r = 0; r < 4; ++r) {
        float m = -3.402823466e38f;
        #pragma unroll
        for (int rr = 0; rr < RPW; ++rr)
          #pragma unroll
          for (int p = 0; p < 4; ++p)
            #pragma unroll
            for (int nf = 0; nf < NF; ++nf)
              m = fmaxf(m, acc[rr][p][of][nf][r]);
        #pragma unroll
        for (int off = 1; off < 16; off <<= 1)
          m = fmaxf(m, __shfl_xor(m, off));
        if (ln == 0)
          red[wv][of * 16 + lg * 4 + r] = m + bias[oc0 + of * 16 + lg * 4 + r];
      }
    __syncthreads();
    if (t < 32) {
      const float v = fmaxf(fmaxf(red[0][t], red[1][t]), fmaxf(red[2][t], red[3][t]));
      mvp[((b * 4) + by) * OC + oc0 + t] = v;
    }
  }
}

// ---------------------------------------------------------------------------
// Conv k5 s1 p2, 192 -> 576, 64x64.  mfma_f32_16x16x32, acc[4][4].
// Round-4 confirmed: pad-80 (0 conflicts) + per-wave rotation + setprio
// = 359 -> 296 us.  This round: (a) rotate ky ONLY (kx compile-time ->
// bx ds_read offsets fold into 16-bit immediates, removing the per-j VALU
// address math the full rotation introduced, VALUBusy 21%); (b) explicit
// 2-slot operand pipeline (ah/bx[2][4], compile-time j&1 slot index) so
// j+1's 8 loads issue while j's 16 MFMAs run (VGPR 84 -> ~150, still >=
// 12 waves/CU; LDS-bound).  X: [b][24 qg][64][64][8].  W: [j][24][576][8].
// ---------------------------------------------------------------------------
__global__ __launch_bounds__(256, 3) void conv3_k(
    const unsigned short* __restrict__ gxh,
    const unsigned short* __restrict__ gwh,
    const float* __restrict__ bias, float* __restrict__ out, int act)
{
  __shared__ __align__(16) unsigned short xs[8][4][80][8];

  const int bid  = blockIdx.x;
  const int orig = (bid & 7) * 288 + (bid >> 3);   // ocg-major chunks per XCD
  const int ocg  = orig >> 8;
  const int rem  = orig & 255;
  const int b    = rem >> 4;
  const int band = rem & 15;
  const int y0   = band * 4;
  const int oc0  = ocg * 64;
  const int t    = threadIdx.x;
  const int wv   = t >> 6;
  const int l    = t & 63;
  const int lg   = l >> 4;      // ic 8-group (quarter) within the 32-ic phase
  const int ln   = l & 15;

  f32x4 acc[4][4];
  #pragma unroll
  for (int of = 0; of < 4; ++of)
    #pragma unroll
    for (int pf = 0; pf < 4; ++pf)
      acc[of][pf] = (f32x4){0.f, 0.f, 0.f, 0.f};

  // per-wave ky rotation (decorrelates the 4 waves' LDS row access + MFMA
  // phase); kx stays compile-time so bx offsets fold into ds immediates
  int ky2v[5], rlv[5];
  #pragma unroll
  for (int ky = 0; ky < 5; ++ky) {
    int k2 = ky + wv; if (k2 >= 5) k2 -= 5;
    ky2v[ky] = k2; rlv[ky] = wv + k2;
  }

  // one-time zero of the tile (covers halo cols + OOB rows; those cells are
  // never rewritten by the gll staging in any phase)
  {
    unsigned short* fx = (unsigned short*)xs;
    const bf16x8 z8 = {0,0,0,0,0,0,0,0};
    #pragma unroll
    for (int k = 0; k < 10; ++k) {
      const int li = t + k * 256;
      if (li < 2560) *(bf16x8*)&fx[li * 8] = z8;
    }
  }

  for (int c = 0; c < 6; ++c) {
    __syncthreads();   // prev compute done (and init-zero visible, c==0)
    // stage 8 rows x 4 quarters: 32 gll, 8 per wave; lane = column
    #pragma unroll
    for (int k = 0; k < 8; ++k) {
      const int idx = k * 4 + wv;
      const int row = idx >> 2, q = idx & 3;
      const int y = y0 - 2 + row;
      if ((unsigned)y < 64u) {
        const unsigned short* g = &gxh[
            ((((size_t)b * 24 + c * 4 + q) << 12) + ((size_t)y << 6) + l) * 8];
        gll16(g, &xs[row][q][2][0]);
      }
    }
    __syncthreads();   // implicit vmcnt(0): staging visible

    // phase bases
    const unsigned short* wrow = gwh + ((size_t)((c * 4 + lg) * 576) + oc0 + ln) * 8;
    const unsigned short* xrow[5];
    #pragma unroll
    for (int ky = 0; ky < 5; ++ky)
      xrow[ky] = &xs[rlv[ky]][lg][ln][0];

    bf16x8 ah[2][4], bx[2][4];

    // slot loader: ky,kx,slot all compile-time at call sites
    #define LDW(KY, KX, S)                                                  \
      {                                                                     \
        const unsigned short* wj = wrow + (size_t)(ky2v[KY] * 5 + (KX)) * 110592; \
        _Pragma("unroll")                                                   \
        for (int of = 0; of < 4; ++of)                                      \
          ah[S][of] = *(const bf16x8*)&wj[of * 128];                        \
        const unsigned short* xr = xrow[KY];                                \
        _Pragma("unroll")                                                   \
        for (int pf = 0; pf < 4; ++pf)                                      \
          bx[S][pf] = *(const bf16x8*)&xr[(pf * 16 + (KX)) * 8];            \
      }

    LDW(0, 0, 0)
    #pragma unroll
    for (int j = 0; j < 25; ++j) {
      const int s = j & 1;
      if (j < 24) {
        const int jn = j + 1;
        const int kyn = jn / 5, kxn = jn % 5;
        const int ns = jn & 1;
        LDW(kyn, kxn, ns)
      }
      __builtin_amdgcn_s_setprio(1);
      #pragma unroll
      for (int of = 0; of < 4; ++of)
        #pragma unroll
        for (int pf = 0; pf < 4; ++pf)
          acc[of][pf] = __builtin_amdgcn_mfma_f32_16x16x32_bf16(
              ah[s][of], bx[s][pf], acc[of][pf], 0, 0, 0);
      __builtin_amdgcn_s_setprio(0);
    }
    #undef LDW
  }

  // epilogue: D mapping (16x16): col = l&15 (px), row = (l>>4)*4 + r (oc)
  const int y = y0 + wv;
  #pragma unroll
  for (int of = 0; of < 4; ++of)
    #pragma unroll
    for (int r = 0; r < 4; ++r) {
      const int oc = oc0 + of * 16 + lg * 4 + r;
      const float bv = bias[oc];
      float* po = &out[(((size_t)(b * 576 + oc) * 64) + y) * 64 + ln];
      #pragma unroll
      for (int pf = 0; pf < 4; ++pf)
        po[16 * pf] = act_r(acc[of][pf][r] + bv, act);
    }
}

// ---------------------------------------------------------------------------
// Weights head: reduce 4 tile-maxes, leaky, 1x1 conv (576x576), softmax K=3
// ---------------------------------------------------------------------------
__global__ __launch_bounds__(256) void head_k(
    const float* __restrict__ mvp, const float* __restrict__ w3,
    const float* __restrict__ b3, float* __restrict__ outw)
{
  __shared__ float lv[576];
  __shared__ float yv[576];
  const int b = blockIdx.x;
  const int t = threadIdx.x;
  for (int i = t; i < 576; i += 256) {
    float m = mvp[(b * 4 + 0) * 576 + i];
    #pragma unroll
    for (int ti = 1; ti < 4; ++ti)
      m = fmaxf(m, mvp[(b * 4 + ti) * 576 + i]);
    lv[i] = m >= 0.f ? m : 0.01f * m;
  }
  __syncthreads();
  for (int oc = t; oc < 576; oc += 256) {
    float s = b3[oc];
    for (int c = 0; c < 576; ++c) s += w3[oc * 576 + c] * lv[c];
    yv[oc] = s;
  }
  __syncthreads();
  if (t < 192) {
    const float v0 = yv[t], v1 = yv[192 + t], v2 = yv[384 + t];
    const float mx = fmaxf(v0, fmaxf(v1, v2));
    const float e0 = expf(v0 - mx), e1 = expf(v1 - mx), e2 = expf(v2 - mx);
    const float inv = 1.f / (e0 + e1 + e2);
    outw[b * 576 + t]       = e0 * inv;
    outw[b * 576 + 192 + t] = e1 * inv;
    outw[b * 576 + 384 + t] = e2 * inv;
  }
}

extern "C" void kernel_launch(void* const* d_in, const int* in_sizes, int n_in,
                              void* d_out, int out_size, void* d_ws, size_t ws_size,
                              hipStream_t stream)
{
  (void)in_sizes; (void)n_in; (void)out_size; (void)ws_size;

  const float* z1    = (const float*)d_in[0];
  const float* gs_w1 = (const float*)d_in[1];
  const float* gs_b1 = (const float*)d_in[2];
  const float* gs_w2 = (const float*)d_in[3];
  const float* gs_b2 = (const float*)d_in[4];
  const float* gs_w3 = (const float*)d_in[5];
  const float* gs_b3 = (const float*)d_in[6];
  const float* gm_w1 = (const float*)d_in[7];
  const float* gm_b1 = (const float*)d_in[8];
  const float* gm_w2 = (const float*)d_in[9];
  const float* gm_b2 = (const float*)d_in[10];
  const float* gm_w3 = (const float*)d_in[11];
  const float* gm_b3 = (const float*)d_in[12];
  const float* gw_w1 = (const float*)d_in[13];
  const float* gw_b1 = (const float*)d_in[14];
  const float* gw_w2 = (const float*)d_in[15];
  const float* gw_b2 = (const float*)d_in[16];
  const float* gw_w3 = (const float*)d_in[17];
  const float* gw_b3 = (const float*)d_in[18];

  // workspace layout (ushort units), total ~38 MB
  unsigned short* p = (unsigned short*)d_ws;
  unsigned short* Z   = p; p += 786432;
  unsigned short* A1  = p; p += (size_t)3 * 3145728;   // 3 branches
  unsigned short* A2  = p; p += 12582912;
  unsigned short* W1  = p; p += (size_t)3 * 921600;    // 3 branch w1
  unsigned short* Wb  = p; p += 2764800;               // reusable big slot
  float* MVp = (float*)p;                              // [16][4][576]

  float* o_sigma = (float*)d_out;
  float* o_means = o_sigma + (size_t)Bsz * 576 * 64 * 64;
  float* o_w     = o_means + (size_t)Bsz * 576 * 64 * 64;

  dim3 blk(256);

  zprep_k<<<dim3(3072), blk, 0, stream>>>(z1, Z);
  wprep1_k<<<dim3(1350), blk, 0, stream>>>(gs_w1, gm_w1, gw_w1, W1);

  // deconv1, all 3 branches in one launch (acts: relu, leaky, leaky)
  deconv2_k<16,1,0,2><<<dim3(6,2,48), blk, 0, stream>>>(
      Z, 0, W1, 921600, gs_b1, gm_b1, gw_b1,
      A1, 3145728, nullptr, 192, 1, 2, 2);

  // sigma branch
  wprep_d_k<<<dim3(450), blk, 0, stream>>>(gs_w2, Wb, 192);
  deconv2_k<32,1,1,1><<<dim3(6,8,16), blk, 0, stream>>>(
      A1, 0, Wb, 0, gs_b2, gs_b2, gs_b2,
      A2, 0, nullptr, 192, 1, 1, 1);
  wprep_t_k<<<dim3(1350), blk, 0, stream>>>(gs_w3, Wb);
  conv3_k<<<dim3(2304), blk, 0, stream>>>(A2, Wb, gs_b3, o_sigma, 1);

  // means branch
  wprep_d_k<<<dim3(450), blk, 0, stream>>>(gm_w2, Wb, 192);
  deconv2_k<32,1,1,1><<<dim3(6,8,16), blk, 0, stream>>>(
      A1 + (size_t)3145728, 0, Wb, 0, gm_b2, gm_b2, gm_b2,
      A2, 0, nullptr, 192, 2, 2, 2);
  wprep_t_k<<<dim3(1350), blk, 0, stream>>>(gm_w3, Wb);
  conv3_k<<<dim3(2304), blk, 0, stream>>>(A2, Wb, gm_b3, o_means, 0);

  // weights branch
  wprep_d_k<<<dim3(1350), blk, 0, stream>>>(gw_w2, Wb, 576);
  deconv2_k<32,2,0,2><<<dim3(18,4,16), blk, 0, stream>>>(
      A1 + (size_t)2 * 3145728, 0, Wb, 0,
      gw_b2, gw_b2, gw_b2, nullptr, 0, MVp, 576, 0, 0, 0);
  head_k<<<dim3(16), blk, 0, stream>>>(MVp, gw_w3, gw_b3, o_w);
}